// Round 9
// baseline (186.671 us; speedup 1.0000x reference)
//
#include <hip/hip_runtime.h>

#define B_   2
#define C_   256
#define N_   4096
#define H_   8
#define HD_  32
#define G_   8
#define CPG_ 32

typedef short short8 __attribute__((ext_vector_type(8)));
typedef short s4v    __attribute__((ext_vector_type(4)));
typedef float f32x4  __attribute__((ext_vector_type(4)));
typedef float f4     __attribute__((ext_vector_type(4)));

__device__ __forceinline__ float b2f(short s) {
    return __uint_as_float(((unsigned)(unsigned short)s) << 16);
}
__device__ __forceinline__ short f2b(float f) {
    unsigned u = __float_as_uint(f);
    unsigned r = (u + 0x7FFF + ((u >> 16) & 1)) >> 16;  // RNE
    return (short)r;
}

// ---------------- GN stats stage 1: 1024 blocks, partial (s,ss) per 1/64-slab ----------------
__global__ __launch_bounds__(256) void gn_part(const float* __restrict__ x,
                                               float* __restrict__ part) {
    int blk = blockIdx.x;            // bg = blk>>6 (16), slice = blk&63
    const f4* p = (const f4*)x + (size_t)(blk >> 6) * (CPG_ * N_ / 4) + (size_t)(blk & 63) * 512;
    float s = 0.f, ss = 0.f;
#pragma unroll
    for (int i = 0; i < 2; i++) {
        f4 v = p[threadIdx.x + i * 256];
#pragma unroll
        for (int j = 0; j < 4; j++) { float f = v[j]; s += f; ss += f * f; }
    }
#pragma unroll
    for (int off = 32; off > 0; off >>= 1) {
        s  += __shfl_down(s, off);
        ss += __shfl_down(ss, off);
    }
    __shared__ float rs[4], rss[4];
    int w = threadIdx.x >> 6;
    if ((threadIdx.x & 63) == 0) { rs[w] = s; rss[w] = ss; }
    __syncthreads();
    if (threadIdx.x == 0) {
        part[blk * 2]     = rs[0] + rs[1] + rs[2] + rs[3];
        part[blk * 2 + 1] = rss[0] + rss[1] + rss[2] + rss[3];
    }
}

// ---------------- GN apply (+inline stats reduce): x[b][c][n] f32 -> xnT[b][n][c] bf16 ----------
__global__ __launch_bounds__(256) void gn_apply(const float* __restrict__ x,
                                                const float* __restrict__ gw,
                                                const float* __restrict__ gb,
                                                const float* __restrict__ part,
                                                short* __restrict__ xnT) {
    int t = blockIdx.x * 256 + threadIdx.x;   // 0..262143
    int n  = t & 4095;                        // fastest across lanes -> coalesced reads
    int c0 = ((t >> 12) & 31) << 3;           // uniform per block
    int b  = t >> 17;                         // uniform per block
    int g  = c0 >> 5;
    int bg = b * 8 + g;
    // uniform scalar reduction of this (b,g)'s 64 partials
    float s = 0.f, ss = 0.f;
#pragma unroll 8
    for (int i = 0; i < 64; i++) {
        s  += part[bg * 128 + i * 2];
        ss += part[bg * 128 + i * 2 + 1];
    }
    const float inv = 1.f / (float)(CPG_ * N_);
    float mu   = s * inv;
    float var  = ss * inv - mu * mu;
    float rstd = rsqrtf(var + 1e-5f);

    const float* xp = x + ((size_t)b * C_ + c0) * N_ + n;
    short8 o;
#pragma unroll
    for (int j = 0; j < 8; j++) {
        float a  = rstd * gw[c0 + j];
        float bb = gb[c0 + j] - mu * a;
        o[j] = f2b(xp[(size_t)j * N_] * a + bb);
    }
    *(short8*)&xnT[((size_t)b * N_ + n) * C_ + c0] = o;
}

// ---------------- Fused QKV GEMM: out = W(256x256,f32->bf16) * xn(bf16) + bias(f32) ----------------
// which==0 -> Q transposed [b][n][c], scaled (folded softmax scale);
// which==1 -> K packed per head [b*8+h][m][32] (operand swap);
// which==2 -> V [b][c][n].
__global__ __launch_bounds__(256) void gemm_qkv(
    const float* __restrict__ wq, const float* __restrict__ wk, const float* __restrict__ wv,
    const float* __restrict__ bq, const float* __restrict__ bk, const float* __restrict__ bv,
    const short* __restrict__ xnT,
    short* __restrict__ q, short* __restrict__ kt, short* __restrict__ v) {
    int z = blockIdx.z;
    int b = z / 3, which = z % 3;
    const float* W    = which == 0 ? wq : (which == 1 ? wk : wv);
    const float* bias = which == 0 ? bq : (which == 1 ? bk : bv);
    const short* X    = xnT + (size_t)b * N_ * C_;
    bool trans = (which != 2);
    float mul = (which == 0) ? (0.17677669529663687f * 1.4426950408889634f) : 1.0f;

    __shared__ short wl[128][40];
    __shared__ short xl[128][40];

    int o0 = blockIdx.y * 128, n0 = blockIdx.x * 128;
    int tid = threadIdx.x;
    int w = tid >> 6, lane = tid & 63, li = lane & 15, quad = lane >> 4;
    int wr = w >> 1, wc = w & 1;

    f32x4 acc[4][4];
#pragma unroll
    for (int i = 0; i < 4; i++)
#pragma unroll
        for (int j = 0; j < 4; j++) acc[i][j] = (f32x4){0.f, 0.f, 0.f, 0.f};

    for (int k0 = 0; k0 < 256; k0 += 32) {
#pragma unroll
        for (int i = 0; i < 2; i++) {
            int idx = tid + i * 256;
            int row = idx >> 2, co = (idx & 3) << 3;
            const float* wp = &W[(size_t)(o0 + row) * 256 + k0 + co];
            f4 wa = *(const f4*)wp;
            f4 wb = *(const f4*)(wp + 4);
            short8 w8;
#pragma unroll
            for (int j = 0; j < 4; j++) { w8[j] = f2b(wa[j]); w8[j + 4] = f2b(wb[j]); }
            *(short8*)&wl[row][co] = w8;
            *(short8*)&xl[row][co] = *(const short8*)&X[(size_t)(n0 + row) * 256 + k0 + co];
        }
        __syncthreads();
        typedef short row40[40];
        row40* at = trans ? xl : wl;
        row40* bt = trans ? wl : xl;
        short8 af[4], bfr[4];
#pragma unroll
        for (int i = 0; i < 4; i++) af[i]  = *(short8*)&at[wr * 64 + i * 16 + li][quad * 8];
#pragma unroll
        for (int j = 0; j < 4; j++) bfr[j] = *(short8*)&bt[wc * 64 + j * 16 + li][quad * 8];
#pragma unroll
        for (int i = 0; i < 4; i++)
#pragma unroll
            for (int j = 0; j < 4; j++)
                acc[i][j] = __builtin_amdgcn_mfma_f32_16x16x32_bf16(af[i], bfr[j], acc[i][j], 0, 0, 0);
        __syncthreads();
    }

    if (which == 2) {          // V [b][c][n]
        short* outp = v + (size_t)b * C_ * N_;
#pragma unroll
        for (int i = 0; i < 4; i++) {
            int ob = o0 + wr * 64 + i * 16 + quad * 4;
#pragma unroll
            for (int j = 0; j < 4; j++) {
                int n_ = n0 + wc * 64 + j * 16 + li;
#pragma unroll
                for (int r = 0; r < 4; r++) {
                    float val = acc[i][j][r] + bias[ob + r];
                    outp[(size_t)(ob + r) * N_ + n_] = f2b(val);
                }
            }
        }
    } else if (which == 0) {   // Q^T [b][n][c], scaled
        short* outp = q + (size_t)b * N_ * C_;
#pragma unroll
        for (int i = 0; i < 4; i++) {
            int nb_ = n0 + wr * 64 + i * 16 + quad * 4;
#pragma unroll
            for (int j = 0; j < 4; j++) {
                int o_ = o0 + wc * 64 + j * 16 + li;
                float bv_ = bias[o_];
#pragma unroll
                for (int r = 0; r < 4; r++)
                    outp[(size_t)(nb_ + r) * C_ + o_] = f2b((acc[i][j][r] + bv_) * mul);
            }
        }
    } else {                   // K packed [b*8+h][m][32]
#pragma unroll
        for (int i = 0; i < 4; i++) {
            int nb_ = n0 + wr * 64 + i * 16 + quad * 4;
#pragma unroll
            for (int j = 0; j < 4; j++) {
                int o_ = o0 + wc * 64 + j * 16 + li;
                int hh = o_ >> 5, d = o_ & 31;
                float bv_ = bias[o_];
                short* kdst = kt + ((size_t)(b * 8 + hh) * N_) * HD_ + d;
#pragma unroll
                for (int r = 0; r < 4; r++)
                    kdst[(size_t)(nb_ + r) * HD_] = f2b(acc[i][j][r] + bv_);
            }
        }
    }
}

// ---------------- Flash v8: 64 Q-rows/block, 1024 blocks (4 blk/CU), LDS-shared dbuf K/V ----------
// QT: [b][n][c] (pre-scaled); KP: [b*8+h][m][32] packed; V: [b][c][n]; O -> aoT [b][n][c].
// 4 waves own disjoint 16-row n-slices, share each K/V tile from LDS. Double occupancy vs v7
// (16 waves/CU cap) to hide the barrier/staging latency; traffic 524 MB still far under
// per-XCD L2 ceiling.
__global__ __launch_bounds__(256) void flash(const short* __restrict__ q,
                                             const short* __restrict__ ktp,
                                             const short* __restrict__ v,
                                             short* __restrict__ aoT) {
    // XCD-aware decode: all 64 blocks of one (b,h) share blockIdx%8 -> same XCD L2
    int bid = blockIdx.x;          // 0..1023
    int xcd = bid & 7;
    int s_  = bid >> 3;            // 0..127
    int bh  = xcd * 2 + (s_ & 1);  // head-pair per XCD
    int nb  = s_ >> 1;             // 0..63
    int b = bh >> 3, h = bh & 7;

    const short* QT = q   + (size_t)b * N_ * C_ + h * HD_;   // QT[n*256 + d]
    const short* KP = ktp + (size_t)bh * N_ * HD_;           // KP[m*32 + d], packed
    const short* V  = v   + ((size_t)b * C_ + h * HD_) * N_; // V[d][m]
    short* O = aoT + (size_t)b * N_ * C_ + h * HD_;          // O[n*256 + d]

    __shared__ short kl[2][64 * 40];    // K tile [m][d], pad 40 (2-way free)
    __shared__ short vl[2][32 * 72];    // V tile [d][m], pad 72
    __shared__ short pl[4 * 16 * 72];   // per-wave P arena (16n x 64m)

    int tid = threadIdx.x, w = tid >> 6, lane = tid & 63, li = lane & 15, quad = lane >> 4;
    int n0w = nb * 64 + w * 16;
    short* plw = pl + w * (16 * 72);

    // B-frag of Q: B[k=d=quad*8+j][col n=li]; one b128 load
    short8 qf = *(const short8*)&QT[(size_t)(n0w + li) * 256 + quad * 8];

    f32x4 oa0 = (f32x4){0.f, 0.f, 0.f, 0.f};  // rows n=quad*4+r, cols d=li
    f32x4 oa1 = (f32x4){0.f, 0.f, 0.f, 0.f};  // cols d=16+li
    float lr = 0.f;
    const f32x4 zero = (f32x4){0.f, 0.f, 0.f, 0.f};

    // cooperative staging addresses (256 threads cover 4KB K + 4KB V per tile)
    int krow = tid >> 2, kcol = (tid & 3) << 3;   // K: 64 rows x 32d
    int vrow = tid >> 3, vcol = (tid & 7) << 3;   // V: 32 rows x 64m
    const short* kgp = KP + (size_t)krow * HD_ + kcol;   // fully sequential stream
    const short* vgp = V + (size_t)vrow * N_ + vcol;
    int klo = krow * 40 + kcol;
    int vlo = vrow * 72 + vcol;

    short8 kst = *(const short8*)kgp;
    short8 vst = *(const short8*)vgp;

    for (int mt = 0; mt < 64; mt++) {
        int buf = mt & 1;
        *(short8*)&kl[buf][klo] = kst;
        *(short8*)&vl[buf][vlo] = vst;
        __syncthreads();
        if (mt < 63) {   // global prefetch of next tile overlaps compute
            kst = *(const short8*)(kgp + (size_t)(mt + 1) * 64 * HD_);
            vst = *(const short8*)(vgp + (mt + 1) * 64);
        }

        // S^T = K * Q^T: lane holds rows m=c*16+quad*4+r, col n=li
        f32x4 s[4];
#pragma unroll
        for (int c = 0; c < 4; c++) {
            short8 kf = *(short8*)&kl[buf][(c * 16 + li) * 40 + quad * 8];
            s[c] = __builtin_amdgcn_mfma_f32_16x16x32_bf16(kf, qf, zero, 0, 0, 0);
        }

        // exp2 (no max), pack to bf16 P^T in LDS, accumulate denominator
        float lp = 0.f;
#pragma unroll
        for (int c = 0; c < 4; c++) {
            float e0 = __builtin_amdgcn_exp2f(s[c][0]);
            float e1 = __builtin_amdgcn_exp2f(s[c][1]);
            float e2 = __builtin_amdgcn_exp2f(s[c][2]);
            float e3 = __builtin_amdgcn_exp2f(s[c][3]);
            lp += (e0 + e1) + (e2 + e3);
            unsigned pk0 = __builtin_amdgcn_perm(__float_as_uint(e1), __float_as_uint(e0), 0x07060302);
            unsigned pk1 = __builtin_amdgcn_perm(__float_as_uint(e3), __float_as_uint(e2), 0x07060302);
            uint2 pkv; pkv.x = pk0; pkv.y = pk1;
            *(uint2*)&plw[li * 72 + c * 16 + quad * 4] = pkv;
        }
        lr += lp;

        // O += P * V
        short8 vf00 = *(short8*)&vl[buf][li * 72 + quad * 8];
        short8 vf01 = *(short8*)&vl[buf][(16 + li) * 72 + quad * 8];
        short8 vf10 = *(short8*)&vl[buf][li * 72 + 32 + quad * 8];
        short8 vf11 = *(short8*)&vl[buf][(16 + li) * 72 + 32 + quad * 8];
        short8 pf0 = *(short8*)&plw[li * 72 + quad * 8];
        short8 pf1 = *(short8*)&plw[li * 72 + 32 + quad * 8];
        oa0 = __builtin_amdgcn_mfma_f32_16x16x32_bf16(pf0, vf00, oa0, 0, 0, 0);
        oa1 = __builtin_amdgcn_mfma_f32_16x16x32_bf16(pf0, vf01, oa1, 0, 0, 0);
        oa0 = __builtin_amdgcn_mfma_f32_16x16x32_bf16(pf1, vf10, oa0, 0, 0, 0);
        oa1 = __builtin_amdgcn_mfma_f32_16x16x32_bf16(pf1, vf11, oa1, 0, 0, 0);
    }

    // denominator: combine 4 quads (same li = same n); per-wave O write (disjoint n)
    lr += __shfl_xor(lr, 16);
    lr += __shfl_xor(lr, 32);
#pragma unroll
    for (int r2 = 0; r2 < 4; r2++) {
        float ln = __shfl(lr, quad * 4 + r2);
        float inv = 1.f / ln;
        size_t n_ = (size_t)(n0w + quad * 4 + r2);
        O[n_ * 256 + li]      = f2b(oa0[r2] * inv);
        O[n_ * 256 + 16 + li] = f2b(oa1[r2] * inv);
    }
}

// ---------------- Out projection + bias + residual -> d_out (f32) ----------------
__global__ __launch_bounds__(256) void gemm_out(const float* __restrict__ W,
                                                const float* __restrict__ bias,
                                                const short* __restrict__ aoT,
                                                const float* __restrict__ resid,
                                                float* __restrict__ out) {
    int b = blockIdx.z;
    const short* X = aoT + (size_t)b * N_ * C_;
    const float* R = resid + (size_t)b * C_ * N_;
    float* outp = out + (size_t)b * C_ * N_;

    __shared__ short wl[128][40];
    __shared__ short xl[128][40];

    int o0 = blockIdx.y * 128, n0 = blockIdx.x * 128;
    int tid = threadIdx.x;
    int w = tid >> 6, lane = tid & 63, li = lane & 15, quad = lane >> 4;
    int wr = w >> 1, wc = w & 1;

    f32x4 acc[4][4];
#pragma unroll
    for (int i = 0; i < 4; i++)
#pragma unroll
        for (int j = 0; j < 4; j++) acc[i][j] = (f32x4){0.f, 0.f, 0.f, 0.f};

    for (int k0 = 0; k0 < 256; k0 += 32) {
#pragma unroll
        for (int i = 0; i < 2; i++) {
            int idx = tid + i * 256;
            int row = idx >> 2, co = (idx & 3) << 3;
            const float* wp = &W[(size_t)(o0 + row) * 256 + k0 + co];
            f4 wa = *(const f4*)wp;
            f4 wb = *(const f4*)(wp + 4);
            short8 w8;
#pragma unroll
            for (int j = 0; j < 4; j++) { w8[j] = f2b(wa[j]); w8[j + 4] = f2b(wb[j]); }
            *(short8*)&wl[row][co] = w8;
            *(short8*)&xl[row][co] = *(const short8*)&X[(size_t)(n0 + row) * 256 + k0 + co];
        }
        __syncthreads();
        short8 af[4], bfr[4];
#pragma unroll
        for (int i = 0; i < 4; i++) af[i]  = *(short8*)&wl[wr * 64 + i * 16 + li][quad * 8];
#pragma unroll
        for (int j = 0; j < 4; j++) bfr[j] = *(short8*)&xl[wc * 64 + j * 16 + li][quad * 8];
#pragma unroll
        for (int i = 0; i < 4; i++)
#pragma unroll
            for (int j = 0; j < 4; j++)
                acc[i][j] = __builtin_amdgcn_mfma_f32_16x16x32_bf16(af[i], bfr[j], acc[i][j], 0, 0, 0);
        __syncthreads();
    }
#pragma unroll
    for (int i = 0; i < 4; i++) {
        int ob = o0 + wr * 64 + i * 16 + quad * 4;
#pragma unroll
        for (int j = 0; j < 4; j++) {
            int n_ = n0 + wc * 64 + j * 16 + li;
#pragma unroll
            for (int r = 0; r < 4; r++) {
                size_t idx = (size_t)(ob + r) * N_ + n_;
                outp[idx] = acc[i][j][r] + bias[ob + r] + R[idx];
            }
        }
    }
}

extern "C" void kernel_launch(void* const* d_in, const int* in_sizes, int n_in,
                              void* d_out, int out_size, void* d_ws, size_t ws_size,
                              hipStream_t stream) {
    const float* x  = (const float*)d_in[0];
    const float* gw = (const float*)d_in[1];
    const float* gb = (const float*)d_in[2];
    const float* wq = (const float*)d_in[3];
    const float* bq = (const float*)d_in[4];
    const float* wk = (const float*)d_in[5];
    const float* bk = (const float*)d_in[6];
    const float* wv = (const float*)d_in[7];
    const float* bv = (const float*)d_in[8];
    const float* wo = (const float*)d_in[9];
    const float* bo = (const float*)d_in[10];
    float* out = (float*)d_out;

    char* ws = (char*)d_ws;
    float* part = (float*)ws;             // 2048 floats
    const size_t TS = (size_t)B_ * N_ * C_;  // 2M elements per bf16 tensor
    short* xnT = (short*)(ws + 16384);
    short* q   = xnT + TS;
    short* kt  = q + TS;    // packed [b*8+h][m][32]
    short* v   = kt + TS;
    short* aoT = xnT;  // alias: xnT dead after gemm_qkv

    gn_part<<<1024, 256, 0, stream>>>(x, part);
    gn_apply<<<1024, 256, 0, stream>>>(x, gw, gb, part, xnT);
    gemm_qkv<<<dim3(32, 2, 6), 256, 0, stream>>>(wq, wk, wv, bq, bk, bv, xnT, q, kt, v);
    flash<<<1024, 256, 0, stream>>>(q, kt, v, aoT);
    gemm_out<<<dim3(32, 2, 2), 256, 0, stream>>>(wo, bo, aoT, x, out);
}

// Round 10
// 185.335 us; speedup vs baseline: 1.0072x; 1.0072x over previous
//
#include <hip/hip_runtime.h>

#define B_   2
#define C_   256
#define N_   4096
#define H_   8
#define HD_  32
#define G_   8
#define CPG_ 32

typedef short short8 __attribute__((ext_vector_type(8)));
typedef short s4v    __attribute__((ext_vector_type(4)));
typedef float f32x4  __attribute__((ext_vector_type(4)));
typedef float f4     __attribute__((ext_vector_type(4)));

__device__ __forceinline__ float b2f(short s) {
    return __uint_as_float(((unsigned)(unsigned short)s) << 16);
}
__device__ __forceinline__ short f2b(float f) {
    unsigned u = __float_as_uint(f);
    unsigned r = (u + 0x7FFF + ((u >> 16) & 1)) >> 16;  // RNE
    return (short)r;
}

// ---------------- GN stats stage 1: 1024 blocks, partial (s,ss) per 1/64-slab ----------------
__global__ __launch_bounds__(256) void gn_part(const float* __restrict__ x,
                                               float* __restrict__ part) {
    int blk = blockIdx.x;            // bg = blk>>6 (16), slice = blk&63
    const f4* p = (const f4*)x + (size_t)(blk >> 6) * (CPG_ * N_ / 4) + (size_t)(blk & 63) * 512;
    float s = 0.f, ss = 0.f;
#pragma unroll
    for (int i = 0; i < 2; i++) {
        f4 v = p[threadIdx.x + i * 256];
#pragma unroll
        for (int j = 0; j < 4; j++) { float f = v[j]; s += f; ss += f * f; }
    }
#pragma unroll
    for (int off = 32; off > 0; off >>= 1) {
        s  += __shfl_down(s, off);
        ss += __shfl_down(ss, off);
    }
    __shared__ float rs[4], rss[4];
    int w = threadIdx.x >> 6;
    if ((threadIdx.x & 63) == 0) { rs[w] = s; rss[w] = ss; }
    __syncthreads();
    if (threadIdx.x == 0) {
        part[blk * 2]     = rs[0] + rs[1] + rs[2] + rs[3];
        part[blk * 2 + 1] = rss[0] + rss[1] + rss[2] + rss[3];
    }
}

// ---------------- GN apply (+inline stats reduce): x[b][c][n] f32 -> xnT[b][n][c] bf16 ----------
__global__ __launch_bounds__(256) void gn_apply(const float* __restrict__ x,
                                                const float* __restrict__ gw,
                                                const float* __restrict__ gb,
                                                const float* __restrict__ part,
                                                short* __restrict__ xnT) {
    int t = blockIdx.x * 256 + threadIdx.x;   // 0..262143
    int n  = t & 4095;                        // fastest across lanes -> coalesced reads
    int c0 = ((t >> 12) & 31) << 3;           // uniform per block
    int b  = t >> 17;                         // uniform per block
    int g  = c0 >> 5;
    int bg = b * 8 + g;
    float s = 0.f, ss = 0.f;
#pragma unroll 8
    for (int i = 0; i < 64; i++) {
        s  += part[bg * 128 + i * 2];
        ss += part[bg * 128 + i * 2 + 1];
    }
    const float inv = 1.f / (float)(CPG_ * N_);
    float mu   = s * inv;
    float var  = ss * inv - mu * mu;
    float rstd = rsqrtf(var + 1e-5f);

    const float* xp = x + ((size_t)b * C_ + c0) * N_ + n;
    short8 o;
#pragma unroll
    for (int j = 0; j < 8; j++) {
        float a  = rstd * gw[c0 + j];
        float bb = gb[c0 + j] - mu * a;
        o[j] = f2b(xp[(size_t)j * N_] * a + bb);
    }
    *(short8*)&xnT[((size_t)b * N_ + n) * C_ + c0] = o;
}

// ---------------- Fused QKV GEMM: 64o x 128n tiles, 768 blocks (3/CU) ----------------
// which==0 -> Q^T [b][n][c] scaled; which==1 -> K packed [b*8+h][m][32]; which==2 -> V [b][c][n].
__global__ __launch_bounds__(256) void gemm_qkv(
    const float* __restrict__ wq, const float* __restrict__ wk, const float* __restrict__ wv,
    const float* __restrict__ bq, const float* __restrict__ bk, const float* __restrict__ bv,
    const short* __restrict__ xnT,
    short* __restrict__ q, short* __restrict__ kt, short* __restrict__ v) {
    int z = blockIdx.z;
    int b = z / 3, which = z % 3;
    const float* W    = which == 0 ? wq : (which == 1 ? wk : wv);
    const float* bias = which == 0 ? bq : (which == 1 ? bk : bv);
    const short* X    = xnT + (size_t)b * N_ * C_;
    bool trans = (which != 2);
    float mul = (which == 0) ? (0.17677669529663687f * 1.4426950408889634f) : 1.0f;

    __shared__ short wl[64][40];    // W-tile [o][k]
    __shared__ short xl[128][40];   // X-tile [n][k]

    int o0 = blockIdx.y * 64, n0 = blockIdx.x * 128;
    int tid = threadIdx.x;
    int w = tid >> 6, lane = tid & 63, li = lane & 15, quad = lane >> 4;
    int wr = w & 1, wc = w >> 1;

    f32x4 acc[8];
#pragma unroll
    for (int i = 0; i < 8; i++) acc[i] = (f32x4){0.f, 0.f, 0.f, 0.f};

    for (int k0 = 0; k0 < 256; k0 += 32) {
        {   // W: 64 rows x 32k -> 1 short8/thread (f32->bf16)
            int row = tid >> 2, co = (tid & 3) << 3;
            const float* wp = &W[(size_t)(o0 + row) * 256 + k0 + co];
            f4 wa = *(const f4*)wp;
            f4 wb = *(const f4*)(wp + 4);
            short8 w8;
#pragma unroll
            for (int j = 0; j < 4; j++) { w8[j] = f2b(wa[j]); w8[j + 4] = f2b(wb[j]); }
            *(short8*)&wl[row][co] = w8;
        }
#pragma unroll
        for (int i = 0; i < 2; i++) {   // X: 128 rows x 32k -> 2 short8/thread
            int idx = tid + i * 256;
            int row = idx >> 2, co = (idx & 3) << 3;
            *(short8*)&xl[row][co] = *(const short8*)&X[(size_t)(n0 + row) * 256 + k0 + co];
        }
        __syncthreads();
        short8 af[4], bfr[4];
        if (trans) {   // rows = n (128 from xl), cols = o (64 from wl): 4x2
#pragma unroll
            for (int i = 0; i < 4; i++) af[i]  = *(short8*)&xl[wr * 64 + i * 16 + li][quad * 8];
#pragma unroll
            for (int j = 0; j < 2; j++) bfr[j] = *(short8*)&wl[wc * 32 + j * 16 + li][quad * 8];
#pragma unroll
            for (int i = 0; i < 4; i++)
#pragma unroll
                for (int j = 0; j < 2; j++)
                    acc[i * 2 + j] = __builtin_amdgcn_mfma_f32_16x16x32_bf16(af[i], bfr[j], acc[i * 2 + j], 0, 0, 0);
        } else {       // rows = o (64 from wl), cols = n (128 from xl): 2x4
#pragma unroll
            for (int i = 0; i < 2; i++) af[i]  = *(short8*)&wl[wr * 32 + i * 16 + li][quad * 8];
#pragma unroll
            for (int j = 0; j < 4; j++) bfr[j] = *(short8*)&xl[wc * 64 + j * 16 + li][quad * 8];
#pragma unroll
            for (int i = 0; i < 2; i++)
#pragma unroll
                for (int j = 0; j < 4; j++)
                    acc[i * 4 + j] = __builtin_amdgcn_mfma_f32_16x16x32_bf16(af[i], bfr[j], acc[i * 4 + j], 0, 0, 0);
        }
        __syncthreads();
    }

    if (which == 2) {          // V [b][c][n]
        short* outp = v + (size_t)b * C_ * N_;
#pragma unroll
        for (int i = 0; i < 2; i++) {
            int ob = o0 + wr * 32 + i * 16 + quad * 4;
#pragma unroll
            for (int j = 0; j < 4; j++) {
                int n_ = n0 + wc * 64 + j * 16 + li;
#pragma unroll
                for (int r = 0; r < 4; r++) {
                    float val = acc[i * 4 + j][r] + bias[ob + r];
                    outp[(size_t)(ob + r) * N_ + n_] = f2b(val);
                }
            }
        }
    } else if (which == 0) {   // Q^T [b][n][c], scaled
        short* outp = q + (size_t)b * N_ * C_;
#pragma unroll
        for (int i = 0; i < 4; i++) {
            int nb_ = n0 + wr * 64 + i * 16 + quad * 4;
#pragma unroll
            for (int j = 0; j < 2; j++) {
                int o_ = o0 + wc * 32 + j * 16 + li;
                float bv_ = bias[o_];
#pragma unroll
                for (int r = 0; r < 4; r++)
                    outp[(size_t)(nb_ + r) * C_ + o_] = f2b((acc[i * 2 + j][r] + bv_) * mul);
            }
        }
    } else {                   // K packed [b*8+h][m][32]
#pragma unroll
        for (int i = 0; i < 4; i++) {
            int nb_ = n0 + wr * 64 + i * 16 + quad * 4;
#pragma unroll
            for (int j = 0; j < 2; j++) {
                int o_ = o0 + wc * 32 + j * 16 + li;
                int hh = o_ >> 5, d = o_ & 31;
                float bv_ = bias[o_];
                short* kdst = kt + ((size_t)(b * 8 + hh) * N_) * HD_ + d;
#pragma unroll
                for (int r = 0; r < 4; r++)
                    kdst[(size_t)(nb_ + r) * HD_] = f2b(acc[i * 2 + j][r] + bv_);
            }
        }
    }
}

// ---------------- Flash v9: 2-wave blocks, 2 Q-groups/wave (K/V frags amortized), dbuf LDS ------
// QT: [b][n][c] (pre-scaled); KP: [b*8+h][m][32] packed; V: [b][c][n]; O -> aoT [b][n][c].
// 1024 blocks (4/CU). Per-16n-unit LDS traffic 10.2 KB vs v8's 14.3 KB.
__global__ __launch_bounds__(128) void flash(const short* __restrict__ q,
                                             const short* __restrict__ ktp,
                                             const short* __restrict__ v,
                                             short* __restrict__ aoT) {
    int bid = blockIdx.x;          // 0..1023
    int xcd = bid & 7;
    int s_  = bid >> 3;            // 0..127
    int bh  = xcd * 2 + (s_ & 1);  // head-pair per XCD
    int nb  = s_ >> 1;             // 0..63
    int b = bh >> 3, h = bh & 7;

    const short* QT = q   + (size_t)b * N_ * C_ + h * HD_;   // QT[n*256 + d]
    const short* KP = ktp + (size_t)bh * N_ * HD_;           // KP[m*32 + d]
    const short* V  = v   + ((size_t)b * C_ + h * HD_) * N_; // V[d][m]
    short* O = aoT + (size_t)b * N_ * C_ + h * HD_;          // O[n*256 + d]

    __shared__ short kl[2][64 * 40];    // K tile [m][d]
    __shared__ short vl[2][32 * 72];    // V tile [d][m]
    __shared__ short pl[2 * 2 * 16 * 72];  // [wave][group] P arenas

    int tid = threadIdx.x, w = tid >> 6, lane = tid & 63, li = lane & 15, quad = lane >> 4;
    int n0w = nb * 64 + w * 32;
    short* plw0 = pl + (w * 2 + 0) * (16 * 72);
    short* plw1 = pl + (w * 2 + 1) * (16 * 72);

    short8 qf0 = *(const short8*)&QT[(size_t)(n0w + li) * 256 + quad * 8];
    short8 qf1 = *(const short8*)&QT[(size_t)(n0w + 16 + li) * 256 + quad * 8];

    f32x4 oa00 = (f32x4){0.f,0.f,0.f,0.f}, oa01 = oa00, oa10 = oa00, oa11 = oa00;
    float lr0 = 0.f, lr1 = 0.f;
    const f32x4 zero = (f32x4){0.f, 0.f, 0.f, 0.f};

    // staging: 128 threads x 2 passes cover 4KB K + 4KB V per tile
    const short* kgp = KP + (size_t)(tid >> 2) * HD_ + (tid & 3) * 8;  // rows 0..31 (+32)
    const short* vgp = V + (size_t)(tid >> 3) * N_ + (tid & 7) * 8;    // d 0..15 (+16)
    int klo = (tid >> 2) * 40 + (tid & 3) * 8;
    int vlo = (tid >> 3) * 72 + (tid & 7) * 8;

    short8 kst0 = *(const short8*)kgp;
    short8 kst1 = *(const short8*)(kgp + (size_t)32 * HD_);
    short8 vst0 = *(const short8*)vgp;
    short8 vst1 = *(const short8*)(vgp + (size_t)16 * N_);

    for (int mt = 0; mt < 64; mt++) {
        int buf = mt & 1;
        *(short8*)&kl[buf][klo] = kst0;
        *(short8*)&kl[buf][klo + 32 * 40] = kst1;
        *(short8*)&vl[buf][vlo] = vst0;
        *(short8*)&vl[buf][vlo + 16 * 72] = vst1;
        __syncthreads();
        if (mt < 63) {
            int m1 = (mt + 1) * 64;
            kst0 = *(const short8*)(kgp + (size_t)m1 * HD_);
            kst1 = *(const short8*)(kgp + (size_t)(m1 + 32) * HD_);
            vst0 = *(const short8*)(vgp + m1);
            vst1 = *(const short8*)(vgp + (size_t)16 * N_ + m1);
        }

        // S^T = K * Q^T for both groups: K-frags read ONCE
        f32x4 s0[4], s1[4];
#pragma unroll
        for (int c = 0; c < 4; c++) {
            short8 kf = *(short8*)&kl[buf][(c * 16 + li) * 40 + quad * 8];
            s0[c] = __builtin_amdgcn_mfma_f32_16x16x32_bf16(kf, qf0, zero, 0, 0, 0);
            s1[c] = __builtin_amdgcn_mfma_f32_16x16x32_bf16(kf, qf1, zero, 0, 0, 0);
        }

        // exp2 + pack (no max), group 0
        {
            float lp = 0.f;
#pragma unroll
            for (int c = 0; c < 4; c++) {
                float e0 = __builtin_amdgcn_exp2f(s0[c][0]);
                float e1 = __builtin_amdgcn_exp2f(s0[c][1]);
                float e2 = __builtin_amdgcn_exp2f(s0[c][2]);
                float e3 = __builtin_amdgcn_exp2f(s0[c][3]);
                lp += (e0 + e1) + (e2 + e3);
                unsigned pk0 = __builtin_amdgcn_perm(__float_as_uint(e1), __float_as_uint(e0), 0x07060302);
                unsigned pk1 = __builtin_amdgcn_perm(__float_as_uint(e3), __float_as_uint(e2), 0x07060302);
                uint2 pkv; pkv.x = pk0; pkv.y = pk1;
                *(uint2*)&plw0[li * 72 + c * 16 + quad * 4] = pkv;
            }
            lr0 += lp;
        }
        // group 1
        {
            float lp = 0.f;
#pragma unroll
            for (int c = 0; c < 4; c++) {
                float e0 = __builtin_amdgcn_exp2f(s1[c][0]);
                float e1 = __builtin_amdgcn_exp2f(s1[c][1]);
                float e2 = __builtin_amdgcn_exp2f(s1[c][2]);
                float e3 = __builtin_amdgcn_exp2f(s1[c][3]);
                lp += (e0 + e1) + (e2 + e3);
                unsigned pk0 = __builtin_amdgcn_perm(__float_as_uint(e1), __float_as_uint(e0), 0x07060302);
                unsigned pk1 = __builtin_amdgcn_perm(__float_as_uint(e3), __float_as_uint(e2), 0x07060302);
                uint2 pkv; pkv.x = pk0; pkv.y = pk1;
                *(uint2*)&plw1[li * 72 + c * 16 + quad * 4] = pkv;
            }
            lr1 += lp;
        }

        // O += P * V: V-frags read ONCE, shared across both groups
        short8 vf00 = *(short8*)&vl[buf][li * 72 + quad * 8];
        short8 vf01 = *(short8*)&vl[buf][(16 + li) * 72 + quad * 8];
        short8 vf10 = *(short8*)&vl[buf][li * 72 + 32 + quad * 8];
        short8 vf11 = *(short8*)&vl[buf][(16 + li) * 72 + 32 + quad * 8];
        short8 pf00 = *(short8*)&plw0[li * 72 + quad * 8];
        short8 pf01 = *(short8*)&plw0[li * 72 + 32 + quad * 8];
        short8 pf10 = *(short8*)&plw1[li * 72 + quad * 8];
        short8 pf11 = *(short8*)&plw1[li * 72 + 32 + quad * 8];
        oa00 = __builtin_amdgcn_mfma_f32_16x16x32_bf16(pf00, vf00, oa00, 0, 0, 0);
        oa01 = __builtin_amdgcn_mfma_f32_16x16x32_bf16(pf00, vf01, oa01, 0, 0, 0);
        oa00 = __builtin_amdgcn_mfma_f32_16x16x32_bf16(pf01, vf10, oa00, 0, 0, 0);
        oa01 = __builtin_amdgcn_mfma_f32_16x16x32_bf16(pf01, vf11, oa01, 0, 0, 0);
        oa10 = __builtin_amdgcn_mfma_f32_16x16x32_bf16(pf10, vf00, oa10, 0, 0, 0);
        oa11 = __builtin_amdgcn_mfma_f32_16x16x32_bf16(pf10, vf01, oa11, 0, 0, 0);
        oa10 = __builtin_amdgcn_mfma_f32_16x16x32_bf16(pf11, vf10, oa10, 0, 0, 0);
        oa11 = __builtin_amdgcn_mfma_f32_16x16x32_bf16(pf11, vf11, oa11, 0, 0, 0);
    }

    // denominators + O writes (per wave, disjoint n)
    lr0 += __shfl_xor(lr0, 16); lr0 += __shfl_xor(lr0, 32);
    lr1 += __shfl_xor(lr1, 16); lr1 += __shfl_xor(lr1, 32);
#pragma unroll
    for (int r2 = 0; r2 < 4; r2++) {
        float ln0 = __shfl(lr0, quad * 4 + r2);
        float inv0 = 1.f / ln0;
        size_t n_ = (size_t)(n0w + quad * 4 + r2);
        O[n_ * 256 + li]      = f2b(oa00[r2] * inv0);
        O[n_ * 256 + 16 + li] = f2b(oa01[r2] * inv0);
        float ln1 = __shfl(lr1, quad * 4 + r2);
        float inv1 = 1.f / ln1;
        size_t n2 = (size_t)(n0w + 16 + quad * 4 + r2);
        O[n2 * 256 + li]      = f2b(oa10[r2] * inv1);
        O[n2 * 256 + 16 + li] = f2b(oa11[r2] * inv1);
    }
}

// ---------------- Out projection: 128o x 64n tiles, 256 blocks (1/CU) ----------------
__global__ __launch_bounds__(256) void gemm_out(const float* __restrict__ W,
                                                const float* __restrict__ bias,
                                                const short* __restrict__ aoT,
                                                const float* __restrict__ resid,
                                                float* __restrict__ out) {
    int b = blockIdx.z;
    const short* X = aoT + (size_t)b * N_ * C_;
    const float* R = resid + (size_t)b * C_ * N_;
    float* outp = out + (size_t)b * C_ * N_;

    __shared__ short wl[128][40];
    __shared__ short xl[64][40];

    int o0 = blockIdx.y * 128, n0 = blockIdx.x * 64;
    int tid = threadIdx.x;
    int w = tid >> 6, lane = tid & 63, li = lane & 15, quad = lane >> 4;
    int wr = w & 1, wc = w >> 1;

    f32x4 acc[4][2];
#pragma unroll
    for (int i = 0; i < 4; i++)
#pragma unroll
        for (int j = 0; j < 2; j++) acc[i][j] = (f32x4){0.f, 0.f, 0.f, 0.f};

    for (int k0 = 0; k0 < 256; k0 += 32) {
#pragma unroll
        for (int i = 0; i < 2; i++) {   // W: 128x32 -> 2/thread
            int idx = tid + i * 256;
            int row = idx >> 2, co = (idx & 3) << 3;
            const float* wp = &W[(size_t)(o0 + row) * 256 + k0 + co];
            f4 wa = *(const f4*)wp;
            f4 wb = *(const f4*)(wp + 4);
            short8 w8;
#pragma unroll
            for (int j = 0; j < 4; j++) { w8[j] = f2b(wa[j]); w8[j + 4] = f2b(wb[j]); }
            *(short8*)&wl[row][co] = w8;
        }
        {   // X: 64x32 -> 1/thread
            int row = tid >> 2, co = (tid & 3) << 3;
            *(short8*)&xl[row][co] = *(const short8*)&X[(size_t)(n0 + row) * 256 + k0 + co];
        }
        __syncthreads();
        short8 af[4], bfr[2];
#pragma unroll
        for (int i = 0; i < 4; i++) af[i]  = *(short8*)&wl[wr * 64 + i * 16 + li][quad * 8];
#pragma unroll
        for (int j = 0; j < 2; j++) bfr[j] = *(short8*)&xl[wc * 32 + j * 16 + li][quad * 8];
#pragma unroll
        for (int i = 0; i < 4; i++)
#pragma unroll
            for (int j = 0; j < 2; j++)
                acc[i][j] = __builtin_amdgcn_mfma_f32_16x16x32_bf16(af[i], bfr[j], acc[i][j], 0, 0, 0);
        __syncthreads();
    }
#pragma unroll
    for (int i = 0; i < 4; i++) {
        int ob = o0 + wr * 64 + i * 16 + quad * 4;
#pragma unroll
        for (int j = 0; j < 2; j++) {
            int n_ = n0 + wc * 32 + j * 16 + li;
#pragma unroll
            for (int r = 0; r < 4; r++) {
                size_t idx = (size_t)(ob + r) * N_ + n_;
                outp[idx] = acc[i][j][r] + bias[ob + r] + R[idx];
            }
        }
    }
}

extern "C" void kernel_launch(void* const* d_in, const int* in_sizes, int n_in,
                              void* d_out, int out_size, void* d_ws, size_t ws_size,
                              hipStream_t stream) {
    const float* x  = (const float*)d_in[0];
    const float* gw = (const float*)d_in[1];
    const float* gb = (const float*)d_in[2];
    const float* wq = (const float*)d_in[3];
    const float* bq = (const float*)d_in[4];
    const float* wk = (const float*)d_in[5];
    const float* bk = (const float*)d_in[6];
    const float* wv = (const float*)d_in[7];
    const float* bv = (const float*)d_in[8];
    const float* wo = (const float*)d_in[9];
    const float* bo = (const float*)d_in[10];
    float* out = (float*)d_out;

    char* ws = (char*)d_ws;
    float* part = (float*)ws;             // 2048 floats
    const size_t TS = (size_t)B_ * N_ * C_;  // 2M elements per bf16 tensor
    short* xnT = (short*)(ws + 16384);
    short* q   = xnT + TS;
    short* kt  = q + TS;    // packed [b*8+h][m][32]
    short* v   = kt + TS;
    short* aoT = xnT;  // alias: xnT dead after gemm_qkv

    gn_part<<<1024, 256, 0, stream>>>(x, part);
    gn_apply<<<1024, 256, 0, stream>>>(x, gw, gb, part, xnT);
    gemm_qkv<<<dim3(32, 4, 6), 256, 0, stream>>>(wq, wk, wv, bq, bk, bv, xnT, q, kt, v);
    flash<<<1024, 128, 0, stream>>>(q, kt, v, aoT);
    gemm_out<<<dim3(64, 2, 2), 256, 0, stream>>>(wo, bo, aoT, x, out);
}